// Round 6
// baseline (98.464 us; speedup 1.0000x reference)
//
#include <hip/hip_runtime.h>
#include <hip/hip_bf16.h>

#define MULC 128
#define IN_DIM 1152
#define NTHREADS 256
#define W1T_PITCH 136   // ushorts; 272 B row stride

typedef __attribute__((ext_vector_type(8))) short bf16x8;
typedef __attribute__((ext_vector_type(4))) float f32x4;
typedef __attribute__((ext_vector_type(4))) unsigned short u16x4;

__device__ __forceinline__ short bfu(float f) {
    __hip_bfloat16 h = __float2bfloat16(f);     // HW cvt, RNE
    return __builtin_bit_cast(short, h);
}

// load one 96 B chunk (6 f32x4, nontemporal) for this lane
#define LOADC(R, kc) {                                                   \
    const f32x4* p_ = (const f32x4*)(xbase + 96 * (kc));                 \
    _Pragma("unroll")                                                    \
    for (int m_ = 0; m_ < 6; ++m_) R[m_] = __builtin_nontemporal_load(p_ + m_); }

// deinterleave 24 floats (u-major, c-minor stride 3) into 3 bf16x8 A-frags
#define FRAGS(F0, F1, F2, R)                                             \
    bf16x8 F0, F1, F2;                                                   \
    _Pragma("unroll")                                                    \
    for (int s_ = 0; s_ < 8; ++s_) {                                     \
        F0[s_] = bfu(R[(3 * s_ + 0) >> 2][(3 * s_ + 0) & 3]);            \
        F1[s_] = bfu(R[(3 * s_ + 1) >> 2][(3 * s_ + 1) & 3]);            \
        F2[s_] = bfu(R[(3 * s_ + 2) >> 2][(3 * s_ + 2) & 3]);            \
    }

#define MFMA_STEP(kc, F0, F1, F2)                                        \
    _Pragma("unroll")                                                    \
    for (int nt = 0; nt < 8; ++nt) {                                     \
        bf16x8 bfr = *(const bf16x8*)&lds[(nt * 16 + li) * W1T_PITCH + (kc) * 32 + g * 8]; \
        acc[0][nt] = __builtin_amdgcn_mfma_f32_16x16x32_bf16(F0, bfr, acc[0][nt], 0, 0, 0); \
        acc[1][nt] = __builtin_amdgcn_mfma_f32_16x16x32_bf16(F1, bfr, acc[1][nt], 0, 0, 0); \
        acc[2][nt] = __builtin_amdgcn_mfma_f32_16x16x32_bf16(F2, bfr, acc[2][nt], 0, 0, 0); \
    }

__global__ __launch_bounds__(NTHREADS, 2)
void nltp_kernel(const float* __restrict__ x, const float* __restrict__ W1,
                 const float* __restrict__ W2, const float* __restrict__ tpw,
                 float* __restrict__ out)
{
    __shared__ __align__(16) unsigned short lds[128 * W1T_PITCH];   // W1^T only
    const int t  = threadIdx.x;
    const int n0 = blockIdx.x * 64;
    const int l  = t & 63;
    const int w  = t >> 6;      // wave 0..3 owns rows [16w, 16w+16)
    const int g  = l >> 4;      // k-group 0..3
    const int li = l & 15;      // row-in-tile

    const float* xbase = x + (size_t)(n0 + 16 * w + li) * IN_DIM + MULC + 24 * g;

    f32x4 A[6], B[6], C[6];
    LOADC(A, 0);                // chunks 0,1 in flight during W1 staging
    LOADC(B, 1);

    // ---- stage W1^T as bf16 (once per block) ----
    for (int it = 0; it < 16; ++it) {
        int tau = it * 256 + t;
        int v   = tau & 127;
        int u   = (tau >> 7) * 4;
        float f0 = W1[(u + 0) * MULC + v];
        float f1 = W1[(u + 1) * MULC + v];
        float f2 = W1[(u + 2) * MULC + v];
        float f3 = W1[(u + 3) * MULC + v];
        u16x4 pk = { (unsigned short)bfu(f0), (unsigned short)bfu(f1),
                     (unsigned short)bfu(f2), (unsigned short)bfu(f3) };
        *(u16x4*)&lds[v * W1T_PITCH + u] = pk;
    }
    __syncthreads();   // the only barrier

    f32x4 acc[3][8];
#pragma unroll
    for (int c = 0; c < 3; ++c)
#pragma unroll
        for (int nt = 0; nt < 8; ++nt)
            acc[c][nt] = (f32x4){0.f, 0.f, 0.f, 0.f};

    // ---- 2-deep pipelined K loop: chunks k+1, k+2 in flight during compute k ----
    LOADC(C, 2);
    { FRAGS(fa0, fa1, fa2, A); MFMA_STEP(0, fa0, fa1, fa2); }
    LOADC(A, 3);
    { FRAGS(fb0, fb1, fb2, B); MFMA_STEP(1, fb0, fb1, fb2); }
    { FRAGS(fc0, fc1, fc2, C); MFMA_STEP(2, fc0, fc1, fc2); }
    { FRAGS(fd0, fd1, fd2, A); MFMA_STEP(3, fd0, fd1, fd2); }

    // ---- epilogue: silu + W2 contraction + 16-lane reduce + TP readout ----
    const float inv = 0.08838834764831845f;  // 1/sqrt(128)
    float w2a[8], w2b[8];
#pragma unroll
    for (int nt = 0; nt < 8; ++nt) {
        float2 p = *(const float2*)(W2 + 2 * (nt * 16 + li));
        w2a[nt] = p.x; w2b[nt] = p.y;
    }
    float pa[3][4], pb[3][4];
#pragma unroll
    for (int c = 0; c < 3; ++c)
#pragma unroll
        for (int rg = 0; rg < 4; ++rg) { pa[c][rg] = 0.f; pb[c][rg] = 0.f; }

#pragma unroll
    for (int c = 0; c < 3; ++c)
#pragma unroll
        for (int nt = 0; nt < 8; ++nt)
#pragma unroll
            for (int rg = 0; rg < 4; ++rg) {
                float y = acc[c][nt][rg] * inv;
                float e = __expf(-y);
                float s = y * __builtin_amdgcn_rcpf(1.f + e);   // silu
                pa[c][rg] += s * w2a[nt];
                pb[c][rg] += s * w2b[nt];
            }

#pragma unroll
    for (int c = 0; c < 3; ++c)
#pragma unroll
        for (int rg = 0; rg < 4; ++rg) {
            float va = pa[c][rg], vb = pb[c][rg];
            va += __shfl_xor(va, 1, 16); vb += __shfl_xor(vb, 1, 16);
            va += __shfl_xor(va, 2, 16); vb += __shfl_xor(vb, 2, 16);
            va += __shfl_xor(va, 4, 16); vb += __shfl_xor(vb, 4, 16);
            va += __shfl_xor(va, 8, 16); vb += __shfl_xor(vb, 8, 16);
            pa[c][rg] = va * inv;
            pb[c][rg] = vb * inv;
        }

    const float tw0 = tpw[0], tw1 = tpw[1], tw2 = tpw[2];
    const float k0 = tw0 * 0.5773502691896258f;   // 1/sqrt(3)
    const float k1 = tw1 * 0.7071067811865476f;   // sqrt(3)/sqrt(6)
    const float s2 = 0.7071067811865476f;
    const float s6 = 0.4082482904638631f;         // 1/sqrt(6)

#pragma unroll
    for (int rg = 0; rg < 4; ++rg) {
        float a_0 = pa[0][rg], a_1 = pa[1][rg], a_2 = pa[2][rg];
        float b_0 = pb[0][rg], b_1 = pb[1][rg], b_2 = pb[2][rg];
        float o0 = k0 * (a_0 * b_0 + a_1 * b_1 + a_2 * b_2);
        float o1 = k1 * (a_1 * b_2 - a_2 * b_1);
        float o2 = k1 * (a_2 * b_0 - a_0 * b_2);
        float o3 = k1 * (a_0 * b_1 - a_1 * b_0);
        float o4 = tw2 * (s2 * (a_2 * b_0 + a_0 * b_2));
        float o5 = tw2 * (s2 * (a_0 * b_1 + a_1 * b_0));
        float o6 = tw2 * (s6 * (2.f * a_1 * b_1 - a_2 * b_2 - a_0 * b_0));
        float o7 = tw2 * (s2 * (a_2 * b_1 + a_1 * b_2));
        float o8 = tw2 * (s2 * (a_2 * b_2 - a_0 * b_0));
        float o = li == 0 ? o0 : li == 1 ? o1 : li == 2 ? o2 : li == 3 ? o3 :
                  li == 4 ? o4 : li == 5 ? o5 : li == 6 ? o6 : li == 7 ? o7 : o8;
        if (li < 9) {
            int row = n0 + 16 * w + 4 * g + rg;
            out[row * 9 + li] = o;
        }
    }
}

extern "C" void kernel_launch(void* const* d_in, const int* in_sizes, int n_in,
                              void* d_out, int out_size, void* d_ws, size_t ws_size,
                              hipStream_t stream) {
    const float* x   = (const float*)d_in[0];
    const float* W1  = (const float*)d_in[1];
    const float* W2  = (const float*)d_in[2];
    const float* tpw = (const float*)d_in[3];
    float* out = (float*)d_out;
    const int n = in_sizes[0] / IN_DIM;            // 131072
    dim3 grid(n / 64);                             // 2048
    nltp_kernel<<<grid, NTHREADS, 0, stream>>>(x, W1, W2, tpw, out);
}

// Round 7
// 81.365 us; speedup vs baseline: 1.2102x; 1.2102x over previous
//
#include <hip/hip_runtime.h>
#include <hip/hip_bf16.h>

#define IN_DIM 1152
#define NTHREADS 256

typedef __attribute__((ext_vector_type(8))) short bf16x8;
typedef __attribute__((ext_vector_type(4))) float f32x4;

typedef const __attribute__((address_space(1))) unsigned int* gas_t;
typedef __attribute__((address_space(3))) unsigned int* las_t;

__device__ __forceinline__ short bfu(float f) {
    __hip_bfloat16 h = __float2bfloat16(f);     // HW cvt, RNE
    return __builtin_bit_cast(short, h);
}

// LDS: ldsW = ushort[128*128] bf16 W1^T, XOR-swizzled octets   (32 KB)
//      ldsX = float4[64*48]  raw f32 x half-tile, swizzled      (48 KB)
// total exactly 80 KB -> 2 blocks/CU.

__global__ __launch_bounds__(NTHREADS, 2)
void nltp_kernel(const float* __restrict__ x, const float* __restrict__ W1,
                 const float* __restrict__ W2, const float* __restrict__ tpw,
                 float* __restrict__ out)
{
    __shared__ __align__(16) unsigned char ldsraw[32768 + 49152];
    unsigned short* ldsW = (unsigned short*)ldsraw;
    float4* ldsX = (float4*)(ldsraw + 32768);

    const int t  = threadIdx.x;
    const int n0 = blockIdx.x * 64;
    const int l  = t & 63;
    const int w  = t >> 6;      // wave 0..3 owns rows [16w,16w+16)
    const int g  = l >> 4;      // k-group 0..3
    const int li = l & 15;      // row-in-tile
    const int lih = li & 7;

    // ---- issue h0 x-staging: 12 fire-and-forget global_load_lds per thread ----
    // LDS linear in slot; source granule pre-swizzled (G = Gp ^ (r&7)) so the
    // swizzled read-back below is conflict-minimal.  Each wave instruction
    // covers 64 consecutive slots = dense ~1KB of global memory.
#pragma unroll
    for (int m = 0; m < 12; ++m) {
        int slot = 256 * m + t;          // 0..3071
        int r    = slot / 48;            // row 0..63
        int Gp   = slot % 48;            // LDS granule position in row
        int G    = Gp ^ (r & 7);         // source granule
        const float* src = x + (size_t)(n0 + r) * IN_DIM + 128 + 4 * G;
        __builtin_amdgcn_global_load_lds((gas_t)(const void*)src,
                                         (las_t)(void*)&ldsX[slot], 16, 0, 0);
    }

    // ---- W1^T staging: coalesced float4 reads, swizzled bf16 LDS writes ----
#pragma unroll 4
    for (int it = 0; it < 16; ++it) {
        int idx = it * 256 + t;          // float4 index over W1
        int u   = idx >> 5;
        int v4  = idx & 31;
        float4 f = ((const float4*)W1)[idx];
        int ug = u >> 3, ur = u & 7;
#pragma unroll
        for (int e = 0; e < 4; ++e) {
            int v = 4 * v4 + e;
            ldsW[v * 128 + ((ug ^ (v & 7)) << 3) + ur] =
                (unsigned short)bfu(e == 0 ? f.x : e == 1 ? f.y : e == 2 ? f.z : f.w);
        }
    }
    __syncthreads();   // drains DMA + W1 writes

    f32x4 acc[3][8];
#pragma unroll
    for (int c = 0; c < 3; ++c)
#pragma unroll
        for (int nt = 0; nt < 8; ++nt)
            acc[c][nt] = (f32x4){0.f, 0.f, 0.f, 0.f};

    const int ar = 16 * w + li;          // this lane's row
#pragma unroll
    for (int h = 0; h < 2; ++h) {
        if (h == 1) {
            __syncthreads();             // h0 reads complete
#pragma unroll
            for (int m = 0; m < 12; ++m) {
                int slot = 256 * m + t;
                int r    = slot / 48;
                int Gp   = slot % 48;
                int G    = Gp ^ (r & 7);
                const float* src = x + (size_t)(n0 + r) * IN_DIM + 128 + 192 + 4 * G;
                __builtin_amdgcn_global_load_lds((gas_t)(const void*)src,
                                                 (las_t)(void*)&ldsX[slot], 16, 0, 0);
            }
            __syncthreads();             // h1 ready
        }
#pragma unroll
        for (int kcl = 0; kcl < 2; ++kcl) {
            const int kk = 2 * h + kcl;
            float4 rv[6];
#pragma unroll
            for (int j = 0; j < 6; ++j)
                rv[j] = ldsX[ar * 48 + ((24 * kcl + 6 * g + j) ^ lih)];
            const float* f = (const float*)rv;
            bf16x8 F0, F1, F2;
#pragma unroll
            for (int s = 0; s < 8; ++s) {
                F0[s] = bfu(f[3 * s + 0]);
                F1[s] = bfu(f[3 * s + 1]);
                F2[s] = bfu(f[3 * s + 2]);
            }
#pragma unroll
            for (int nt = 0; nt < 8; ++nt) {
                bf16x8 bfr = *(const bf16x8*)&ldsW[(nt * 16 + li) * 128 + (((4 * kk + g) ^ lih) << 3)];
                acc[0][nt] = __builtin_amdgcn_mfma_f32_16x16x32_bf16(F0, bfr, acc[0][nt], 0, 0, 0);
                acc[1][nt] = __builtin_amdgcn_mfma_f32_16x16x32_bf16(F1, bfr, acc[1][nt], 0, 0, 0);
                acc[2][nt] = __builtin_amdgcn_mfma_f32_16x16x32_bf16(F2, bfr, acc[2][nt], 0, 0, 0);
            }
        }
    }

    // ---- epilogue: silu + W2 contraction + 16-lane reduce + TP readout ----
    const float inv = 0.08838834764831845f;  // 1/sqrt(128)
    float w2a[8], w2b[8];
#pragma unroll
    for (int nt = 0; nt < 8; ++nt) {
        float2 p = *(const float2*)(W2 + 2 * (nt * 16 + li));
        w2a[nt] = p.x; w2b[nt] = p.y;
    }
    float pa[3][4], pb[3][4];
#pragma unroll
    for (int c = 0; c < 3; ++c)
#pragma unroll
        for (int rg = 0; rg < 4; ++rg) { pa[c][rg] = 0.f; pb[c][rg] = 0.f; }

#pragma unroll
    for (int c = 0; c < 3; ++c)
#pragma unroll
        for (int nt = 0; nt < 8; ++nt)
#pragma unroll
            for (int rg = 0; rg < 4; ++rg) {
                float y = acc[c][nt][rg] * inv;
                float s = y / (1.f + __expf(-y));   // silu
                pa[c][rg] += s * w2a[nt];
                pb[c][rg] += s * w2b[nt];
            }

#pragma unroll
    for (int c = 0; c < 3; ++c)
#pragma unroll
        for (int rg = 0; rg < 4; ++rg) {
            float va = pa[c][rg], vb = pb[c][rg];
            va += __shfl_xor(va, 1, 16); vb += __shfl_xor(vb, 1, 16);
            va += __shfl_xor(va, 2, 16); vb += __shfl_xor(vb, 2, 16);
            va += __shfl_xor(va, 4, 16); vb += __shfl_xor(vb, 4, 16);
            va += __shfl_xor(va, 8, 16); vb += __shfl_xor(vb, 8, 16);
            pa[c][rg] = va * inv;
            pb[c][rg] = vb * inv;
        }

    const float tw0 = tpw[0], tw1 = tpw[1], tw2 = tpw[2];
    const float k0 = tw0 * 0.5773502691896258f;   // 1/sqrt(3)
    const float k1 = tw1 * 0.7071067811865476f;   // sqrt(3)/sqrt(6)
    const float s2 = 0.7071067811865476f;
    const float s6 = 0.4082482904638631f;         // 1/sqrt(6)

#pragma unroll
    for (int rg = 0; rg < 4; ++rg) {
        float a_0 = pa[0][rg], a_1 = pa[1][rg], a_2 = pa[2][rg];
        float b_0 = pb[0][rg], b_1 = pb[1][rg], b_2 = pb[2][rg];
        float o0 = k0 * (a_0 * b_0 + a_1 * b_1 + a_2 * b_2);
        float o1 = k1 * (a_1 * b_2 - a_2 * b_1);
        float o2 = k1 * (a_2 * b_0 - a_0 * b_2);
        float o3 = k1 * (a_0 * b_1 - a_1 * b_0);
        float o4 = tw2 * (s2 * (a_2 * b_0 + a_0 * b_2));
        float o5 = tw2 * (s2 * (a_0 * b_1 + a_1 * b_0));
        float o6 = tw2 * (s6 * (2.f * a_1 * b_1 - a_2 * b_2 - a_0 * b_0));
        float o7 = tw2 * (s2 * (a_2 * b_1 + a_1 * b_2));
        float o8 = tw2 * (s2 * (a_2 * b_2 - a_0 * b_0));
        float o = li == 0 ? o0 : li == 1 ? o1 : li == 2 ? o2 : li == 3 ? o3 :
                  li == 4 ? o4 : li == 5 ? o5 : li == 6 ? o6 : li == 7 ? o7 : o8;
        if (li < 9) {
            int row = n0 + 16 * w + 4 * g + rg;
            out[row * 9 + li] = o;
        }
    }
}

extern "C" void kernel_launch(void* const* d_in, const int* in_sizes, int n_in,
                              void* d_out, int out_size, void* d_ws, size_t ws_size,
                              hipStream_t stream) {
    const float* x   = (const float*)d_in[0];
    const float* W1  = (const float*)d_in[1];
    const float* W2  = (const float*)d_in[2];
    const float* tpw = (const float*)d_in[3];
    float* out = (float*)d_out;
    const int n = in_sizes[0] / IN_DIM;            // 131072
    dim3 grid(n / 64);                             // 2048
    nltp_kernel<<<grid, NTHREADS, 0, stream>>>(x, W1, W2, tpw, out);
}